// Round 13
// baseline (645.377 us; speedup 1.0000x reference)
//
#include <hip/hip_runtime.h>

typedef __attribute__((ext_vector_type(8))) short s16x8;
typedef __attribute__((ext_vector_type(4))) short s16x4;
typedef __attribute__((ext_vector_type(4))) float f32x4;

#define DEVI __device__ __forceinline__

DEVI unsigned short f2bf(float f){
  unsigned int u = __float_as_uint(f);
  return (unsigned short)((u + 0x7fffu + ((u >> 16) & 1u)) >> 16);
}

DEVI s16x8 mk8(s16x4 a, s16x4 b){
  s16x8 r;
  r[0]=a[0]; r[1]=a[1]; r[2]=a[2]; r[3]=a[3];
  r[4]=b[0]; r[5]=b[1]; r[6]=b[2]; r[7]=b[3];
  return r;
}

DEVI f32x4 mfma16(s16x8 a, s16x8 b, f32x4 c){
  return __builtin_amdgcn_mfma_f32_16x16x32_bf16(a, b, c, 0, 0, 0);
}

DEVI void gload16(const unsigned short* g, unsigned short* l){
  __builtin_amdgcn_global_load_lds((const __attribute__((address_space(1))) void*)g,
                                   (__attribute__((address_space(3))) void*)l, 16, 0, 0);
}

// ---------------- fp32 -> bf16 conversion of all GEMM operands ----------------
__global__ __launch_bounds__(256) void cvt_all_k(
    const float* __restrict__ q, const float* __restrict__ k, const float* __restrict__ v,
    const float* __restrict__ wq, const float* __restrict__ wk,
    const float* __restrict__ wv, const float* __restrict__ wo,
    unsigned short* __restrict__ ws)
{
  int bi = blockIdx.x, tid = threadIdx.x;
  const float* src; unsigned short* dst; int base;
  if (bi < 3072){
    int t = bi >> 10;
    src = (t==0) ? q : ((t==1) ? k : v);
    dst = ws + t*4194304;
    base = (bi & 1023) * 4096;
  } else {
    int t = (bi - 3072) >> 8;
    src = (t==0) ? wq : ((t==1) ? wk : ((t==2) ? wv : wo));
    dst = ws + 12582912 + t*1048576;
    base = ((bi - 3072) & 255) * 4096;
  }
  #pragma unroll
  for (int it = 0; it < 4; ++it){
    int i = base + it*1024 + tid*4;
    float4 f = *(const float4*)(src + i);
    s16x4 o;
    o[0] = (short)f2bf(f.x); o[1] = (short)f2bf(f.y);
    o[2] = (short)f2bf(f.z); o[3] = (short)f2bf(f.w);
    *(s16x4*)(dst + i) = o;
  }
}

// ---------------- projection GEMM: y = x @ W^T + b (z = 0:Q 1:K 2:V) ----------
// Fragments are pair-contiguous (k = 8g..8g+7): ONE ds_read_b128 per fragment.
// Matched-tau across A and B keeps the dot product exact for any k-bijection.
__global__ __launch_bounds__(256) void proj_k(
    const unsigned short* __restrict__ Xall, const unsigned short* __restrict__ Wall,
    const float* __restrict__ bq, const float* __restrict__ bk, const float* __restrict__ bv,
    unsigned short* __restrict__ QK, unsigned short* __restrict__ Vt)
{
  __shared__ unsigned short Asm[2][4096];
  __shared__ unsigned short Bsm[2][4096];
  const int tid = threadIdx.x, lane = tid & 63;
  const int w = tid >> 6, g = lane >> 4, ln = lane & 15;
  const int z = blockIdx.z;
  const int m0 = blockIdx.y * 128, n0 = blockIdx.x * 128;
  const int wm = w >> 1, wn = w & 1;
  const unsigned short* A  = Xall + z * 4194304;
  const unsigned short* Bw = Wall + z * 1048576;
  const float* bias = (z==0) ? bq : ((z==1) ? bk : bv);

  f32x4 acc[4][4];
  #pragma unroll
  for (int i=0;i<4;++i)
    #pragma unroll
    for (int j=0;j<4;++j) acc[i][j] = (f32x4){0.f,0.f,0.f,0.f};

  auto stage = [&](int buf, int kt){
    #pragma unroll
    for (int r=0;r<2;++r){
      int c = r*256 + tid;
      int row = c >> 2, cs = (c & 3) ^ ((row >> 1) & 3);
      gload16(A + (m0+row)*1024 + kt*32 + cs*8, &Asm[buf][(r*256 + (tid & 192))*8]);
    }
    #pragma unroll
    for (int r=0;r<2;++r){
      int c = r*256 + tid;
      int row = c >> 2, cs = (c & 3) ^ ((row >> 1) & 3);
      gload16(Bw + (n0+row)*1024 + kt*32 + cs*8, &Bsm[buf][(r*256 + (tid & 192))*8]);
    }
  };

  stage(0, 0);
  for (int kt = 0; kt < 32; ++kt){
    __syncthreads();
    if (kt + 1 < 32) stage((kt+1)&1, kt+1);
    const unsigned short* As = Asm[kt&1];
    const unsigned short* Bs = Bsm[kt&1];
    s16x8 af[4], bfr[4];
    #pragma unroll
    for (int mf=0; mf<4; ++mf){
      int row = wm*64 + mf*16 + ln;
      af[mf] = *(const s16x8*)(As + row*32 + ((g ^ ((row>>1)&3))<<3));
    }
    #pragma unroll
    for (int nf=0; nf<4; ++nf){
      int row = wn*64 + nf*16 + ln;
      bfr[nf] = *(const s16x8*)(Bs + row*32 + ((g ^ ((row>>1)&3))<<3));
    }
    if (z < 2){
      #pragma unroll
      for (int i=0; i<4; ++i)      // i: feature tile (A=W)
        #pragma unroll
        for (int j=0; j<4; ++j)    // j: token tile (B=X)
          acc[i][j] = mfma16(bfr[i], af[j], acc[i][j]);
    } else {
      #pragma unroll
      for (int i=0; i<4; ++i)      // i: token tile (A=X)
        #pragma unroll
        for (int j=0; j<4; ++j)    // j: feature tile (B=W)
          acc[i][j] = mfma16(af[i], bfr[j], acc[i][j]);
    }
  }

  if (z < 2){
    // D rows = features (i, g*4+r), cols = tokens (j, ln): d-contiguous s16x4 stores
    unsigned short* O = QK + z * 4194304;   // [B,H,L,D] bf16
    #pragma unroll
    for (int i=0; i<4; ++i){
      int fb = n0 + wn*64 + i*16 + g*4;
      f32x4 b4 = *(const f32x4*)&bias[fb];
      int hh = fb >> 6, d = fb & 63;
      #pragma unroll
      for (int j=0; j<4; ++j){
        int token = m0 + wm*64 + j*16 + ln;
        int bb = token >> 10, l = token & 1023;
        s16x4 o;
        #pragma unroll
        for (int r=0;r<4;++r){
          float val = acc[i][j][r] + b4[r];
          if (z == 0) val *= 0.125f;
          o[r] = (short)f2bf(val);
        }
        *(s16x4*)(&O[((bb*16 + hh)*1024 + l)*64 + d]) = o;
      }
    }
  } else {
    // D rows = tokens (i, g*4+r), cols = features (j, ln): l-contiguous into V^T
    #pragma unroll
    for (int nf=0; nf<4; ++nf){
      int n = n0 + wn*64 + nf*16 + ln;
      float bv_ = bias[n];
      int hh = n >> 6, d = n & 63;
      #pragma unroll
      for (int mf=0; mf<4; ++mf){
        int mb = m0 + wm*64 + mf*16 + g*4;
        int bb = mb >> 10, l = mb & 1023;
        s16x4 o;
        #pragma unroll
        for (int r=0;r<4;++r) o[r] = (short)f2bf(acc[mf][nf][r] + bv_);
        *(s16x4*)(Vt + ((bb*16 + hh)*64 + d)*1024 + l) = o;   // V^T [B,H,D,L]
      }
    }
  }
}

// ---------------- fused attention, two-pass recompute, ZERO staging ----------------
// K/V/Q are L2/L3-resident (16 MB total, shared by 16 q-tile blocks per bh):
// fragments load DIRECTLY from global (matched-tau: contiguous k-chunks on both
// QK^T operands; PV V-chunks at ks*32+g*4 / +16 match the register-P layout).
// No Ks/Vs/Qs LDS, no per-kt barriers; only madd (4KB) + one barrier.
__global__ __launch_bounds__(256, 4) void attn_k(
    const unsigned short* __restrict__ Qp, const unsigned short* __restrict__ Kp,
    const unsigned short* __restrict__ Vt, const int* __restrict__ mask,
    float* __restrict__ attn, unsigned short* __restrict__ Ob)
{
  __shared__ float madd[1024];

  const int tid = threadIdx.x, lane = tid & 63;
  const int w = tid >> 6, g = lane >> 4, ln = lane & 15;
  const int qt = blockIdx.x, bh = blockIdx.y, b = bh >> 4, h = bh & 15;
  const int q0 = qt * 64;

  const unsigned short* Kg = Kp + bh*65536;   // [L=1024][D=64]
  const unsigned short* Vg = Vt + bh*65536;   // [D=64][L=1024]

  {
    int4 mv = *(const int4*)(mask + b*1024 + tid*4);
    f32x4 md;
    md[0] = mv.x ? (float)mv.x : -9e15f;
    md[1] = mv.y ? (float)mv.y : -9e15f;
    md[2] = mv.z ? (float)mv.z : -9e15f;
    md[3] = mv.w ? (float)mv.w : -9e15f;
    *(f32x4*)(&madd[tid*4]) = md;
  }

  s16x8 qf[2];
  {
    int qrow = q0 + w*16 + ln;
    #pragma unroll
    for (int ks=0; ks<2; ++ks)
      qf[ks] = *(const s16x8*)(Qp + (bh*1024 + qrow)*64 + (ks*4 + g)*8);
  }
  __syncthreads();

  // ---- pass 1: row sums (S^T recompute pattern) ----
  float rsum = 0.f;
  for (int kt = 0; kt < 16; ++kt){
    f32x4 sacc[4];
    #pragma unroll
    for (int nf=0;nf<4;++nf) sacc[nf] = (f32x4){0.f,0.f,0.f,0.f};
    __builtin_amdgcn_s_setprio(1);
    #pragma unroll
    for (int ks=0; ks<2; ++ks){
      #pragma unroll
      for (int nf=0; nf<4; ++nf){
        s16x8 kf = *(const s16x8*)(Kg + (kt*64 + nf*16 + ln)*64 + (ks*4 + g)*8);
        sacc[nf] = mfma16(kf, qf[ks], sacc[nf]);
      }
    }
    __builtin_amdgcn_s_setprio(0);
    #pragma unroll
    for (int nf=0; nf<4; ++nf){
      f32x4 md = *(const f32x4*)&madd[kt*64 + nf*16 + g*4];
      #pragma unroll
      for (int r=0;r<4;++r){
        float s = fminf(fmaxf(sacc[nf][r], -50000.f), 50000.f);
        rsum += __expf(s + md[r]);
      }
    }
  }
  rsum += __shfl_xor(rsum, 16);
  rsum += __shfl_xor(rsum, 32);
  const float inv = (rsum > 0.f) ? (1.f / rsum) : 0.f;

  // ---- pass 2: recompute S, write normalized attn, PV accumulate ----
  f32x4 oacc[4];
  #pragma unroll
  for (int dt=0;dt<4;++dt) oacc[dt] = (f32x4){0.f,0.f,0.f,0.f};

  float* arow = attn + (bh*1024 + q0 + w*16 + ln)*1024;

  for (int kt = 0; kt < 16; ++kt){
    f32x4 sacc[4];
    #pragma unroll
    for (int nf=0;nf<4;++nf) sacc[nf] = (f32x4){0.f,0.f,0.f,0.f};
    __builtin_amdgcn_s_setprio(1);
    #pragma unroll
    for (int ks=0; ks<2; ++ks){
      #pragma unroll
      for (int nf=0; nf<4; ++nf){
        s16x8 kf = *(const s16x8*)(Kg + (kt*64 + nf*16 + ln)*64 + (ks*4 + g)*8);
        sacc[nf] = mfma16(kf, qf[ks], sacc[nf]);
      }
    }
    __builtin_amdgcn_s_setprio(0);
    s16x4 pb[4];
    #pragma unroll
    for (int nf=0; nf<4; ++nf){
      f32x4 md = *(const f32x4*)&madd[kt*64 + nf*16 + g*4];
      f32x4 av;
      #pragma unroll
      for (int r=0;r<4;++r){
        float s = fminf(fmaxf(sacc[nf][r], -50000.f), 50000.f);
        float p = __expf(s + md[r]);
        pb[nf][r] = (short)f2bf(p);
        av[r] = p * inv;
      }
      *(f32x4*)(arow + kt*64 + nf*16 + g*4) = av;
    }
    s16x8 pf0 = mk8(pb[0], pb[1]);
    s16x8 pf1 = mk8(pb[2], pb[3]);
    __builtin_amdgcn_s_setprio(1);
    #pragma unroll
    for (int ks=0; ks<2; ++ks){
      s16x8 pfc = ks ? pf1 : pf0;
      #pragma unroll
      for (int dt=0; dt<4; ++dt){
        const unsigned short* vp = Vg + (dt*16 + ln)*1024 + kt*64 + ks*32 + g*4;
        s16x4 lo = *(const s16x4*)(vp);
        s16x4 hi = *(const s16x4*)(vp + 16);
        oacc[dt] = mfma16(mk8(lo, hi), pfc, oacc[dt]);
      }
    }
    __builtin_amdgcn_s_setprio(0);
  }

  #pragma unroll
  for (int dt=0; dt<4; ++dt){
    s16x4 o;
    #pragma unroll
    for (int r=0;r<4;++r) o[r] = (short)f2bf(oacc[dt][r] * inv);
    *(s16x4*)(Ob + (b*1024 + q0 + w*16 + ln)*1024 + h*64 + dt*16 + g*4) = o;
  }
}

// ---------------- output projection: out = O @ Wo^T + bo (fp32 out) ----------
// Operand-swapped (A=Wo, B=X); pair-contiguous b128 fragments.
__global__ __launch_bounds__(256) void outproj_k(
    const unsigned short* __restrict__ A, const unsigned short* __restrict__ Bw,
    const float* __restrict__ bias, float* __restrict__ O)
{
  __shared__ unsigned short Asm[2][4096];
  __shared__ unsigned short Bsm[2][4096];
  const int tid = threadIdx.x, lane = tid & 63;
  const int w = tid >> 6, g = lane >> 4, ln = lane & 15;
  const int m0 = blockIdx.y * 128, n0 = blockIdx.x * 128;
  const int wm = w >> 1, wn = w & 1;

  f32x4 acc[4][4];
  #pragma unroll
  for (int i=0;i<4;++i)
    #pragma unroll
    for (int j=0;j<4;++j) acc[i][j] = (f32x4){0.f,0.f,0.f,0.f};

  auto stage = [&](int buf, int kt){
    #pragma unroll
    for (int r=0;r<2;++r){
      int c = r*256 + tid;
      int row = c >> 2, cs = (c & 3) ^ ((row >> 1) & 3);
      gload16(A + (m0+row)*1024 + kt*32 + cs*8, &Asm[buf][(r*256 + (tid & 192))*8]);
    }
    #pragma unroll
    for (int r=0;r<2;++r){
      int c = r*256 + tid;
      int row = c >> 2, cs = (c & 3) ^ ((row >> 1) & 3);
      gload16(Bw + (n0+row)*1024 + kt*32 + cs*8, &Bsm[buf][(r*256 + (tid & 192))*8]);
    }
  };

  stage(0, 0);
  for (int kt = 0; kt < 32; ++kt){
    __syncthreads();
    if (kt + 1 < 32) stage((kt+1)&1, kt+1);
    const unsigned short* As = Asm[kt&1];
    const unsigned short* Bs = Bsm[kt&1];
    s16x8 af[4], bfr[4];
    #pragma unroll
    for (int mf=0; mf<4; ++mf){
      int row = wm*64 + mf*16 + ln;
      af[mf] = *(const s16x8*)(As + row*32 + ((g ^ ((row>>1)&3))<<3));
    }
    #pragma unroll
    for (int nf=0; nf<4; ++nf){
      int row = wn*64 + nf*16 + ln;
      bfr[nf] = *(const s16x8*)(Bs + row*32 + ((g ^ ((row>>1)&3))<<3));
    }
    #pragma unroll
    for (int i=0; i<4; ++i)        // i: feature tile (A=Wo)
      #pragma unroll
      for (int j=0; j<4; ++j)      // j: token tile (B=X)
        acc[i][j] = mfma16(bfr[i], af[j], acc[i][j]);
  }

  #pragma unroll
  for (int i=0; i<4; ++i){
    int fb = n0 + wn*64 + i*16 + g*4;
    f32x4 b4 = *(const f32x4*)&bias[fb];
    #pragma unroll
    for (int j=0; j<4; ++j){
      int token = m0 + wm*64 + j*16 + ln;
      f32x4 ov;
      #pragma unroll
      for (int r=0;r<4;++r) ov[r] = acc[i][j][r] + b4[r];
      *(f32x4*)(&O[token*1024 + fb]) = ov;
    }
  }
}

extern "C" void kernel_launch(void* const* d_in, const int* in_sizes, int n_in,
                              void* d_out, int out_size, void* d_ws, size_t ws_size,
                              hipStream_t stream) {
  (void)in_sizes; (void)n_in; (void)out_size; (void)ws_size;
  const float* q  = (const float*)d_in[0];
  const float* k  = (const float*)d_in[1];
  const float* v  = (const float*)d_in[2];
  const int* mask = (const int*)d_in[3];
  const float* Wq = (const float*)d_in[4];  const float* bq = (const float*)d_in[5];
  const float* Wk = (const float*)d_in[6];  const float* bk = (const float*)d_in[7];
  const float* Wv = (const float*)d_in[8];  const float* bv = (const float*)d_in[9];
  const float* Wo = (const float*)d_in[10]; const float* bo = (const float*)d_in[11];

  unsigned short* ws = (unsigned short*)d_ws;
  // ws layout (ushort elements), total 56 MB:
  //   [0,12M)   q,k,v bf16 (3 x 4M)   -- q region reused as Ob after proj
  //   [12M,16M) Wq,Wk,Wv,Wo bf16 (4 x 1M)
  //   [16M,24M) Qp,Kp projected (2 x 4M)
  //   [24M,28M) Vt (V^T, 4M)
  unsigned short* xb   = ws;
  unsigned short* wb   = ws + 12582912;
  unsigned short* Qp   = ws + 16777216;
  unsigned short* Vtb  = ws + 25165824;
  unsigned short* Ob   = ws;               // aliases consumed q-bf16 region

  float* outp  = (float*)d_out;
  float* attnp = outp + 4194304;

  cvt_all_k<<<4096, 256, 0, stream>>>(q, k, v, Wq, Wk, Wv, Wo, ws);
  proj_k<<<dim3(8, 32, 3), 256, 0, stream>>>(xb, wb, bq, bk, bv, Qp, Vtb);
  attn_k<<<dim3(16, 64), 256, 0, stream>>>(Qp, Qp + 4194304, Vtb, mask, attnp, Ob);
  outproj_k<<<dim3(8, 32), 256, 0, stream>>>(Ob, wb + 3145728, bo, outp);
}

// Round 15
// 473.957 us; speedup vs baseline: 1.3617x; 1.3617x over previous
//
#include <hip/hip_runtime.h>

typedef __attribute__((ext_vector_type(8))) short s16x8;
typedef __attribute__((ext_vector_type(4))) short s16x4;
typedef __attribute__((ext_vector_type(4))) float f32x4;

#define DEVI __device__ __forceinline__

DEVI unsigned short f2bf(float f){
  unsigned int u = __float_as_uint(f);
  return (unsigned short)((u + 0x7fffu + ((u >> 16) & 1u)) >> 16);
}

DEVI s16x8 mk8(s16x4 a, s16x4 b){
  s16x8 r;
  r[0]=a[0]; r[1]=a[1]; r[2]=a[2]; r[3]=a[3];
  r[4]=b[0]; r[5]=b[1]; r[6]=b[2]; r[7]=b[3];
  return r;
}

DEVI f32x4 mfma16(s16x8 a, s16x8 b, f32x4 c){
  return __builtin_amdgcn_mfma_f32_16x16x32_bf16(a, b, c, 0, 0, 0);
}

DEVI void gload16(const unsigned short* g, unsigned short* l){
  __builtin_amdgcn_global_load_lds((const __attribute__((address_space(1))) void*)g,
                                   (__attribute__((address_space(3))) void*)l, 16, 0, 0);
}

// ---------------- fp32 -> bf16 conversion of all GEMM operands ----------------
__global__ __launch_bounds__(256) void cvt_all_k(
    const float* __restrict__ q, const float* __restrict__ k, const float* __restrict__ v,
    const float* __restrict__ wq, const float* __restrict__ wk,
    const float* __restrict__ wv, const float* __restrict__ wo,
    unsigned short* __restrict__ ws)
{
  int bi = blockIdx.x, tid = threadIdx.x;
  const float* src; unsigned short* dst; int base;
  if (bi < 3072){
    int t = bi >> 10;
    src = (t==0) ? q : ((t==1) ? k : v);
    dst = ws + t*4194304;
    base = (bi & 1023) * 4096;
  } else {
    int t = (bi - 3072) >> 8;
    src = (t==0) ? wq : ((t==1) ? wk : ((t==2) ? wv : wo));
    dst = ws + 12582912 + t*1048576;
    base = ((bi - 3072) & 255) * 4096;
  }
  #pragma unroll
  for (int it = 0; it < 4; ++it){
    int i = base + it*1024 + tid*4;
    float4 f = *(const float4*)(src + i);
    s16x4 o;
    o[0] = (short)f2bf(f.x); o[1] = (short)f2bf(f.y);
    o[2] = (short)f2bf(f.z); o[3] = (short)f2bf(f.w);
    *(s16x4*)(dst + i) = o;
  }
}

// ---------------- projection GEMM: y = x @ W^T + b (z = 0:Q 1:K 2:V) ----------
// Fragments are pair-contiguous (k = 8g..8g+7): ONE ds_read_b128 per fragment.
// Matched-tau across A and B keeps the dot product exact for any k-bijection.
__global__ __launch_bounds__(256) void proj_k(
    const unsigned short* __restrict__ Xall, const unsigned short* __restrict__ Wall,
    const float* __restrict__ bq, const float* __restrict__ bk, const float* __restrict__ bv,
    unsigned short* __restrict__ QK, unsigned short* __restrict__ Vt)
{
  __shared__ unsigned short Asm[2][4096];
  __shared__ unsigned short Bsm[2][4096];
  const int tid = threadIdx.x, lane = tid & 63;
  const int w = tid >> 6, g = lane >> 4, ln = lane & 15;
  const int z = blockIdx.z;
  const int m0 = blockIdx.y * 128, n0 = blockIdx.x * 128;
  const int wm = w >> 1, wn = w & 1;
  const unsigned short* A  = Xall + z * 4194304;
  const unsigned short* Bw = Wall + z * 1048576;
  const float* bias = (z==0) ? bq : ((z==1) ? bk : bv);

  f32x4 acc[4][4];
  #pragma unroll
  for (int i=0;i<4;++i)
    #pragma unroll
    for (int j=0;j<4;++j) acc[i][j] = (f32x4){0.f,0.f,0.f,0.f};

  auto stage = [&](int buf, int kt){
    #pragma unroll
    for (int r=0;r<2;++r){
      int c = r*256 + tid;
      int row = c >> 2, cs = (c & 3) ^ ((row >> 1) & 3);
      gload16(A + (m0+row)*1024 + kt*32 + cs*8, &Asm[buf][(r*256 + (tid & 192))*8]);
    }
    #pragma unroll
    for (int r=0;r<2;++r){
      int c = r*256 + tid;
      int row = c >> 2, cs = (c & 3) ^ ((row >> 1) & 3);
      gload16(Bw + (n0+row)*1024 + kt*32 + cs*8, &Bsm[buf][(r*256 + (tid & 192))*8]);
    }
  };

  stage(0, 0);
  for (int kt = 0; kt < 32; ++kt){
    __syncthreads();
    if (kt + 1 < 32) stage((kt+1)&1, kt+1);
    const unsigned short* As = Asm[kt&1];
    const unsigned short* Bs = Bsm[kt&1];
    s16x8 af[4], bfr[4];
    #pragma unroll
    for (int mf=0; mf<4; ++mf){
      int row = wm*64 + mf*16 + ln;
      af[mf] = *(const s16x8*)(As + row*32 + ((g ^ ((row>>1)&3))<<3));
    }
    #pragma unroll
    for (int nf=0; nf<4; ++nf){
      int row = wn*64 + nf*16 + ln;
      bfr[nf] = *(const s16x8*)(Bs + row*32 + ((g ^ ((row>>1)&3))<<3));
    }
    if (z < 2){
      #pragma unroll
      for (int i=0; i<4; ++i)      // i: feature tile (A=W)
        #pragma unroll
        for (int j=0; j<4; ++j)    // j: token tile (B=X)
          acc[i][j] = mfma16(bfr[i], af[j], acc[i][j]);
    } else {
      #pragma unroll
      for (int i=0; i<4; ++i)      // i: token tile (A=X)
        #pragma unroll
        for (int j=0; j<4; ++j)    // j: feature tile (B=W)
          acc[i][j] = mfma16(af[i], bfr[j], acc[i][j]);
    }
  }

  if (z < 2){
    // D rows = features (i, g*4+r), cols = tokens (j, ln): d-contiguous s16x4 stores
    unsigned short* O = QK + z * 4194304;   // [B,H,L,D] bf16
    #pragma unroll
    for (int i=0; i<4; ++i){
      int fb = n0 + wn*64 + i*16 + g*4;
      f32x4 b4 = *(const f32x4*)&bias[fb];
      int hh = fb >> 6, d = fb & 63;
      #pragma unroll
      for (int j=0; j<4; ++j){
        int token = m0 + wm*64 + j*16 + ln;
        int bb = token >> 10, l = token & 1023;
        s16x4 o;
        #pragma unroll
        for (int r=0;r<4;++r){
          float val = acc[i][j][r] + b4[r];
          if (z == 0) val *= 0.125f;
          o[r] = (short)f2bf(val);
        }
        *(s16x4*)(&O[((bb*16 + hh)*1024 + l)*64 + d]) = o;
      }
    }
  } else {
    // D rows = tokens (i, g*4+r), cols = features (j, ln): l-contiguous into V^T
    #pragma unroll
    for (int nf=0; nf<4; ++nf){
      int n = n0 + wn*64 + nf*16 + ln;
      float bv_ = bias[n];
      int hh = n >> 6, d = n & 63;
      #pragma unroll
      for (int mf=0; mf<4; ++mf){
        int mb = m0 + wm*64 + mf*16 + g*4;
        int bb = mb >> 10, l = mb & 1023;
        s16x4 o;
        #pragma unroll
        for (int r=0;r<4;++r) o[r] = (short)f2bf(acc[mf][nf][r] + bv_);
        *(s16x4*)(Vt + ((bb*16 + hh)*64 + d)*1024 + l) = o;   // V^T [B,H,D,L]
      }
    }
  }
}

// ---------------- fused attention, two-pass recompute, K/V staged ----------------
// REVERT of round-13 zero-staging (latency-bound, FETCH 113MB): K/V go back
// through coalesced global_load_lds double-buffers. Q fragments direct from
// global (read once; verified round 13). LDS 36KB -> 4 blocks/CU.
// Grid is (bh, qt): same-bh blocks sit at wgid stride 64 (== 0 mod 8 XCDs),
// so one XCD's L2 serves all 16 q-tiles of a head (2MB K/V per XCD).
__global__ __launch_bounds__(256, 4) void attn_k(
    const unsigned short* __restrict__ Qp, const unsigned short* __restrict__ Kp,
    const unsigned short* __restrict__ Vt, const int* __restrict__ mask,
    float* __restrict__ attn, unsigned short* __restrict__ Ob)
{
  __shared__ unsigned short Ks[2][4096];
  __shared__ unsigned short Vs[2][4096];
  __shared__ float madd[1024];

  const int tid = threadIdx.x, lane = tid & 63;
  const int w = tid >> 6, g = lane >> 4, ln = lane & 15;
  const int bh = blockIdx.x, qt = blockIdx.y, b = bh >> 4, h = bh & 15;
  const int q0 = qt * 64;

  auto stage64 = [&](unsigned short* dstbuf, const unsigned short* srcbase, int rowStride){
    #pragma unroll
    for (int r=0;r<2;++r){
      int c = r*256 + tid;
      int row = c >> 3, cs = (c & 7) ^ (row & 7);
      gload16(srcbase + row*rowStride + cs*8, dstbuf + (r*256 + (tid & 192))*8);
    }
  };

  stage64(Ks[0], Kp + bh*65536, 64);
  {
    int4 mv = *(const int4*)(mask + b*1024 + tid*4);
    f32x4 md;
    md[0] = mv.x ? (float)mv.x : -9e15f;
    md[1] = mv.y ? (float)mv.y : -9e15f;
    md[2] = mv.z ? (float)mv.z : -9e15f;
    md[3] = mv.w ? (float)mv.w : -9e15f;
    *(f32x4*)(&madd[tid*4]) = md;
  }

  // Q fragments direct from global (pair-contiguous tau, matches K's LDS tau)
  s16x8 qf[2];
  {
    int qrow = q0 + w*16 + ln;
    #pragma unroll
    for (int ks=0; ks<2; ++ks)
      qf[ks] = *(const s16x8*)(Qp + (bh*1024 + qrow)*64 + (ks*4 + g)*8);
  }
  __syncthreads();

  // ---- pass 1: row sums (S^T recompute pattern) ----
  float rsum = 0.f;
  for (int kt = 0; kt < 16; ++kt){
    if (kt + 1 < 16) stage64(Ks[(kt+1)&1], Kp + bh*65536 + (kt+1)*4096, 64);
    const unsigned short* Kc = Ks[kt&1];
    f32x4 sacc[4];
    #pragma unroll
    for (int nf=0;nf<4;++nf) sacc[nf] = (f32x4){0.f,0.f,0.f,0.f};
    __builtin_amdgcn_s_setprio(1);
    #pragma unroll
    for (int ks=0; ks<2; ++ks){
      #pragma unroll
      for (int nf=0; nf<4; ++nf){
        int row = nf*16 + ln;
        s16x8 kf = *(const s16x8*)(Kc + row*64 + (((ks*4 + g) ^ (row & 7)) << 3));
        sacc[nf] = mfma16(kf, qf[ks], sacc[nf]);
      }
    }
    __builtin_amdgcn_s_setprio(0);
    #pragma unroll
    for (int nf=0; nf<4; ++nf){
      f32x4 md = *(const f32x4*)&madd[kt*64 + nf*16 + g*4];
      #pragma unroll
      for (int r=0;r<4;++r){
        float s = fminf(fmaxf(sacc[nf][r], -50000.f), 50000.f);
        rsum += __expf(s + md[r]);
      }
    }
    __syncthreads();
  }
  rsum += __shfl_xor(rsum, 16);
  rsum += __shfl_xor(rsum, 32);
  const float inv = (rsum > 0.f) ? (1.f / rsum) : 0.f;

  // ---- pass 2: recompute S, write normalized attn, PV accumulate ----
  stage64(Ks[0], Kp + bh*65536, 64);
  stage64(Vs[0], Vt + bh*65536, 1024);
  __syncthreads();

  f32x4 oacc[4];
  #pragma unroll
  for (int dt=0;dt<4;++dt) oacc[dt] = (f32x4){0.f,0.f,0.f,0.f};

  float* arow = attn + (bh*1024 + q0 + w*16 + ln)*1024;

  for (int kt = 0; kt < 16; ++kt){
    if (kt + 1 < 16){
      stage64(Ks[(kt+1)&1], Kp + bh*65536 + (kt+1)*4096, 64);
      stage64(Vs[(kt+1)&1], Vt + bh*65536 + (kt+1)*64, 1024);
    }
    const unsigned short* Kc = Ks[kt&1];
    const unsigned short* Vc = Vs[kt&1];
    f32x4 sacc[4];
    #pragma unroll
    for (int nf=0;nf<4;++nf) sacc[nf] = (f32x4){0.f,0.f,0.f,0.f};
    __builtin_amdgcn_s_setprio(1);
    #pragma unroll
    for (int ks=0; ks<2; ++ks){
      #pragma unroll
      for (int nf=0; nf<4; ++nf){
        int row = nf*16 + ln;
        s16x8 kf = *(const s16x8*)(Kc + row*64 + (((ks*4 + g) ^ (row & 7)) << 3));
        sacc[nf] = mfma16(kf, qf[ks], sacc[nf]);
      }
    }
    __builtin_amdgcn_s_setprio(0);
    s16x4 pb[4];
    #pragma unroll
    for (int nf=0; nf<4; ++nf){
      f32x4 md = *(const f32x4*)&madd[kt*64 + nf*16 + g*4];
      f32x4 av;
      #pragma unroll
      for (int r=0;r<4;++r){
        float s = fminf(fmaxf(sacc[nf][r], -50000.f), 50000.f);
        float p = __expf(s + md[r]);
        pb[nf][r] = (short)f2bf(p);
        av[r] = p * inv;
      }
      *(f32x4*)(arow + kt*64 + nf*16 + g*4) = av;
    }
    s16x8 pf0 = mk8(pb[0], pb[1]);
    s16x8 pf1 = mk8(pb[2], pb[3]);
    __builtin_amdgcn_s_setprio(1);
    #pragma unroll
    for (int ks=0; ks<2; ++ks){
      s16x8 pfc = ks ? pf1 : pf0;
      #pragma unroll
      for (int dt=0; dt<4; ++dt){
        int row = dt*16 + ln, xr = (row & 7) << 1;
        const unsigned short* vp = Vc + row*64;
        s16x4 lo = *(const s16x4*)(vp + (((ks*8 + g) ^ xr) << 2));
        s16x4 hi = *(const s16x4*)(vp + (((ks*8 + g + 4) ^ xr) << 2));
        oacc[dt] = mfma16(mk8(lo, hi), pfc, oacc[dt]);
      }
    }
    __builtin_amdgcn_s_setprio(0);
    __syncthreads();
  }

  #pragma unroll
  for (int dt=0; dt<4; ++dt){
    s16x4 o;
    #pragma unroll
    for (int r=0;r<4;++r) o[r] = (short)f2bf(oacc[dt][r] * inv);
    *(s16x4*)(Ob + (b*1024 + q0 + w*16 + ln)*1024 + h*64 + dt*16 + g*4) = o;
  }
}

// ---------------- output projection: out = O @ Wo^T + bo (fp32 out) ----------
// Operand-swapped (A=Wo, B=X); pair-contiguous b128 fragments.
__global__ __launch_bounds__(256) void outproj_k(
    const unsigned short* __restrict__ A, const unsigned short* __restrict__ Bw,
    const float* __restrict__ bias, float* __restrict__ O)
{
  __shared__ unsigned short Asm[2][4096];
  __shared__ unsigned short Bsm[2][4096];
  const int tid = threadIdx.x, lane = tid & 63;
  const int w = tid >> 6, g = lane >> 4, ln = lane & 15;
  const int m0 = blockIdx.y * 128, n0 = blockIdx.x * 128;
  const int wm = w >> 1, wn = w & 1;

  f32x4 acc[4][4];
  #pragma unroll
  for (int i=0;i<4;++i)
    #pragma unroll
    for (int j=0;j<4;++j) acc[i][j] = (f32x4){0.f,0.f,0.f,0.f};

  auto stage = [&](int buf, int kt){
    #pragma unroll
    for (int r=0;r<2;++r){
      int c = r*256 + tid;
      int row = c >> 2, cs = (c & 3) ^ ((row >> 1) & 3);
      gload16(A + (m0+row)*1024 + kt*32 + cs*8, &Asm[buf][(r*256 + (tid & 192))*8]);
    }
    #pragma unroll
    for (int r=0;r<2;++r){
      int c = r*256 + tid;
      int row = c >> 2, cs = (c & 3) ^ ((row >> 1) & 3);
      gload16(Bw + (n0+row)*1024 + kt*32 + cs*8, &Bsm[buf][(r*256 + (tid & 192))*8]);
    }
  };

  stage(0, 0);
  for (int kt = 0; kt < 32; ++kt){
    __syncthreads();
    if (kt + 1 < 32) stage((kt+1)&1, kt+1);
    const unsigned short* As = Asm[kt&1];
    const unsigned short* Bs = Bsm[kt&1];
    s16x8 af[4], bfr[4];
    #pragma unroll
    for (int mf=0; mf<4; ++mf){
      int row = wm*64 + mf*16 + ln;
      af[mf] = *(const s16x8*)(As + row*32 + ((g ^ ((row>>1)&3))<<3));
    }
    #pragma unroll
    for (int nf=0; nf<4; ++nf){
      int row = wn*64 + nf*16 + ln;
      bfr[nf] = *(const s16x8*)(Bs + row*32 + ((g ^ ((row>>1)&3))<<3));
    }
    #pragma unroll
    for (int i=0; i<4; ++i)        // i: feature tile (A=Wo)
      #pragma unroll
      for (int j=0; j<4; ++j)      // j: token tile (B=X)
        acc[i][j] = mfma16(bfr[i], af[j], acc[i][j]);
  }

  #pragma unroll
  for (int i=0; i<4; ++i){
    int fb = n0 + wn*64 + i*16 + g*4;
    f32x4 b4 = *(const f32x4*)&bias[fb];
    #pragma unroll
    for (int j=0; j<4; ++j){
      int token = m0 + wm*64 + j*16 + ln;
      f32x4 ov;
      #pragma unroll
      for (int r=0;r<4;++r) ov[r] = acc[i][j][r] + b4[r];
      *(f32x4*)(&O[token*1024 + fb]) = ov;
    }
  }
}

extern "C" void kernel_launch(void* const* d_in, const int* in_sizes, int n_in,
                              void* d_out, int out_size, void* d_ws, size_t ws_size,
                              hipStream_t stream) {
  (void)in_sizes; (void)n_in; (void)out_size; (void)ws_size;
  const float* q  = (const float*)d_in[0];
  const float* k  = (const float*)d_in[1];
  const float* v  = (const float*)d_in[2];
  const int* mask = (const int*)d_in[3];
  const float* Wq = (const float*)d_in[4];  const float* bq = (const float*)d_in[5];
  const float* Wk = (const float*)d_in[6];  const float* bk = (const float*)d_in[7];
  const float* Wv = (const float*)d_in[8];  const float* bv = (const float*)d_in[9];
  const float* Wo = (const float*)d_in[10]; const float* bo = (const float*)d_in[11];

  unsigned short* ws = (unsigned short*)d_ws;
  // ws layout (ushort elements), total 56 MB:
  //   [0,12M)   q,k,v bf16 (3 x 4M)   -- q region reused as Ob after proj
  //   [12M,16M) Wq,Wk,Wv,Wo bf16 (4 x 1M)
  //   [16M,24M) Qp,Kp projected (2 x 4M)
  //   [24M,28M) Vt (V^T, 4M)
  unsigned short* xb   = ws;
  unsigned short* wb   = ws + 12582912;
  unsigned short* Qp   = ws + 16777216;
  unsigned short* Vtb  = ws + 25165824;
  unsigned short* Ob   = ws;               // aliases consumed q-bf16 region

  float* outp  = (float*)d_out;
  float* attnp = outp + 4194304;

  cvt_all_k<<<4096, 256, 0, stream>>>(q, k, v, Wq, Wk, Wv, Wo, ws);
  proj_k<<<dim3(8, 32, 3), 256, 0, stream>>>(xb, wb, bq, bk, bv, Qp, Vtb);
  attn_k<<<dim3(64, 16), 256, 0, stream>>>(Qp, Qp + 4194304, Vtb, mask, attnp, Ob);
  outproj_k<<<dim3(8, 32), 256, 0, stream>>>(Ob, wb + 3145728, bo, outp);
}